// Round 3
// baseline (523.765 us; speedup 1.0000x reference)
//
#include <hip/hip_runtime.h>
#include <hip/hip_bf16.h>

// Problem constants
#define N_IN  2048
#define N_HID 4096
#define N_OUT 1024
#define N_TOT 7168
#define BATCH 4096
#define LDA2  (N_IN + N_HID)   // 6144: [x | H] activation buffer leading dim
#define OUT_ELEMS ((size_t)BATCH * N_OUT)

typedef __attribute__((ext_vector_type(8))) short short8;
typedef __attribute__((ext_vector_type(4))) float f32x4;

static __device__ __forceinline__ unsigned short f2bf(float f) {
  __hip_bfloat16 h = __float2bfloat16(f);
  return __builtin_bit_cast(unsigned short, h);
}

// ---------------------------------------------------------------------------
// Convert x (BATCH x N_IN fp32) -> bf16 into A2[:, 0:2048] (row stride 6144)
// ---------------------------------------------------------------------------
__global__ void conv_x_kernel(const float* __restrict__ x,
                              unsigned short* __restrict__ A2) {
  int idx = blockIdx.x * 256 + threadIdx.x;     // BATCH*N_IN/4 threads
  int row = idx >> 9;                           // N_IN/4 = 512 groups per row
  int col = (idx & 511) << 2;
  const float4 v = *(const float4*)(x + (size_t)row * N_IN + col);
  ushort4 o;
  o.x = f2bf(v.x); o.y = f2bf(v.y); o.z = f2bf(v.z); o.w = f2bf(v.w);
  *(ushort4*)(A2 + (size_t)row * LDA2 + col) = o;
}

// ---------------------------------------------------------------------------
// Transpose-convert: dst[n][k] = (bf16)src[k][n]
// src: SK x SN fp32 region with row stride lds_; dst: SN x SK bf16, stride ldd
// 32x32 tiles, 256 threads.
// ---------------------------------------------------------------------------
__global__ void conv_t_kernel(const float* __restrict__ src, int lds_,
                              unsigned short* __restrict__ dst, int ldd,
                              int SK, int SN) {
  __shared__ float tile[32][33];
  const int t = threadIdx.x;
  const int k0 = blockIdx.y << 5, n0 = blockIdx.x << 5;
  const int r = t >> 3, c = (t & 7) << 2;
  const float4 v = *(const float4*)(src + (size_t)(k0 + r) * lds_ + n0 + c);
  tile[r][c] = v.x; tile[r][c + 1] = v.y; tile[r][c + 2] = v.z; tile[r][c + 3] = v.w;
  __syncthreads();
  ushort4 o;
  o.x = f2bf(tile[c][r]);
  o.y = f2bf(tile[c + 1][r]);
  o.z = f2bf(tile[c + 2][r]);
  o.w = f2bf(tile[c + 3][r]);
  *(ushort4*)(dst + (size_t)(n0 + r) * ldd + k0 + c) = o;
}

// ---------------------------------------------------------------------------
// Sum of 4 split-K partial buffers -> d_out (float4, coalesced).
// ---------------------------------------------------------------------------
__global__ void add4_kernel(const float* __restrict__ P, float* __restrict__ out) {
  size_t i = ((size_t)blockIdx.x * 256 + threadIdx.x) * 4;
  float4 a = *(const float4*)(P + i);
  float4 b = *(const float4*)(P + OUT_ELEMS + i);
  float4 c = *(const float4*)(P + 2 * OUT_ELEMS + i);
  float4 d = *(const float4*)(P + 3 * OUT_ELEMS + i);
  float4 o;
  o.x = (a.x + b.x) + (c.x + d.x);
  o.y = (a.y + b.y) + (c.y + d.y);
  o.z = (a.z + b.z) + (c.z + d.z);
  o.w = (a.w + b.w) + (c.w + d.w);
  *(float4*)(out + i) = o;
}

// ---------------------------------------------------------------------------
// GEMM: C = A @ B, A row-major (M x K bf16, stride lda), Bt row-major
// (N x K bf16, stride ldb). 128x128 tile, BK=64, 4 waves x (64x64),
// 16x16x32 bf16 MFMA, global_load_lds width-16 staging.
//
// LDS K-loop layout is XOR-swizzled (R1): staging permutes the per-lane
// global source column, readers XOR the chunk index with (row&7) ->
// fragment ds_read_b128 is 2-way max (free, m136).
//
// Epilogue (R3): C-tile round-trips through LDS with bank-padded strides so
// global stores are coalesced 16B/lane (256B row bursts) instead of scalar
// strided stores. WMODE 1 = relu+bf16 (one 128x128 bf16 pass, stride 136);
// WMODE 0 = fp32 to partial buffer Cv + blockIdx.z*zstride (two 64x128 fp32
// passes, stride 132; pass p is written by waves with wy==p).
// ---------------------------------------------------------------------------
template <int WMODE>
__global__ __launch_bounds__(256)
void gemm_bt(const unsigned short* __restrict__ A, int lda,
             const unsigned short* __restrict__ Bt, int ldb,
             void* __restrict__ Cv, int ldc, int Klen, size_t zstride) {
  // staging: 2 x 128x64 bf16 = 32768 B; epilogue bf16: 128*136*2 = 34816 B;
  // epilogue fp32: 64*132*4 = 33792 B. LDS block = 34816 -> 4 blocks/CU.
  __shared__ __align__(16) char smem[34816];
  unsigned short* As = (unsigned short*)smem;
  unsigned short* Bs = (unsigned short*)(smem + 16384);

  const int tid  = threadIdx.x;
  const int lane = tid & 63;
  const int wave = tid >> 6;
  const int wy = wave >> 1, wx = wave & 1;
  const int lm = lane & 15, quad = lane >> 4;
  const int bm = blockIdx.y, bn = blockIdx.x;
  const int ko0 = blockIdx.z * Klen;

  // staging: LDS chunk index = wave*256 + i*64 + lane -> row=idx>>3, phys
  // chunk=lane&7. Source column is swizzled: logical chunk = (lane&7)^(lane>>3)
  const int grow = (wave << 5) + (lane >> 3);
  const int gcol = ((lane & 7) ^ (lane >> 3)) << 3;

  const unsigned short* Ag = A  + (size_t)(bm * 128 + grow) * lda + gcol + ko0;
  const unsigned short* Bg = Bt + (size_t)(bn * 128 + grow) * ldb + gcol + ko0;
  unsigned short* Asl = As + wave * 2048;
  unsigned short* Bsl = Bs + wave * 2048;

  f32x4 acc[4][4];
#pragma unroll
  for (int i = 0; i < 4; ++i)
#pragma unroll
    for (int j = 0; j < 4; ++j)
      acc[i][j] = (f32x4){0.f, 0.f, 0.f, 0.f};

  for (int ko = 0; ko < Klen; ko += 64) {
    __syncthreads();   // previous iter's compute done before overwrite
#pragma unroll
    for (int i = 0; i < 4; ++i) {
      __builtin_amdgcn_global_load_lds(
          (const __attribute__((address_space(1))) void*)(Ag + (size_t)(8 * i) * lda + ko),
          (__attribute__((address_space(3))) void*)(Asl + i * 512), 16, 0, 0);
      __builtin_amdgcn_global_load_lds(
          (const __attribute__((address_space(1))) void*)(Bg + (size_t)(8 * i) * ldb + ko),
          (__attribute__((address_space(3))) void*)(Bsl + i * 512), 16, 0, 0);
    }
    __syncthreads();   // s_waitcnt vmcnt(0) + barrier

#pragma unroll
    for (int kk = 0; kk < 2; ++kk) {
      short8 av[4], bv[4];
#pragma unroll
      for (int mt = 0; mt < 4; ++mt) {
        const int r = wy * 64 + mt * 16 + lm;
        av[mt] = *(const short8*)(As + r * 64 + (((kk * 4 + quad) ^ (lm & 7)) << 3));
      }
#pragma unroll
      for (int nt = 0; nt < 4; ++nt) {
        const int r = wx * 64 + nt * 16 + lm;
        bv[nt] = *(const short8*)(Bs + r * 64 + (((kk * 4 + quad) ^ (lm & 7)) << 3));
      }
#pragma unroll
      for (int mt = 0; mt < 4; ++mt)
#pragma unroll
        for (int nt = 0; nt < 4; ++nt)
          acc[mt][nt] = __builtin_amdgcn_mfma_f32_16x16x32_bf16(
              av[mt], bv[nt], acc[mt][nt], 0, 0, 0);
    }
  }

  // ---- epilogue: C/D layout col = lane&15, row = quad*4 + reg [m89] ----
  __syncthreads();   // all waves done reading As/Bs before smem reuse

  if (WMODE == 1) {
    // relu + bf16, full 128x128 tile in LDS, padded stride 136 shorts.
    unsigned short* Cs = (unsigned short*)smem;
#pragma unroll
    for (int mt = 0; mt < 4; ++mt) {
      const int row0 = wy * 64 + mt * 16 + quad * 4;
#pragma unroll
      for (int nt = 0; nt < 4; ++nt) {
        const int col = wx * 64 + nt * 16 + lm;
#pragma unroll
        for (int r = 0; r < 4; ++r) {
          float v = acc[mt][nt][r];
          Cs[(row0 + r) * 136 + col] = f2bf(v > 0.f ? v : 0.f);
        }
      }
    }
    __syncthreads();
    unsigned short* C = (unsigned short*)Cv;
    const int col = (tid & 15) << 3;        // 16 lanes x 16B = 256B per row
#pragma unroll
    for (int i = 0; i < 8; ++i) {
      const int row = (tid >> 4) + 16 * i;
      short8 v = *(const short8*)(Cs + row * 136 + col);
      *(short8*)(C + (size_t)(bm * 128 + row) * ldc + bn * 128 + col) = v;
    }
  } else {
    // fp32 partial store, two 64x128 passes, padded stride 132 floats.
    float* Csf = (float*)smem;
    float* C = (float*)Cv + (size_t)blockIdx.z * zstride;
#pragma unroll
    for (int p = 0; p < 2; ++p) {
      if (wy == p) {
#pragma unroll
        for (int mt = 0; mt < 4; ++mt) {
          const int row0 = mt * 16 + quad * 4;   // local row within half-tile
#pragma unroll
          for (int nt = 0; nt < 4; ++nt) {
            const int col = wx * 64 + nt * 16 + lm;
#pragma unroll
            for (int r = 0; r < 4; ++r)
              Csf[(row0 + r) * 132 + col] = acc[mt][nt][r];
          }
        }
      }
      __syncthreads();
      const int col = (tid & 31) << 2;      // 32 lanes x 16B = 512B per row
#pragma unroll
      for (int i = 0; i < 8; ++i) {
        const int row = (tid >> 5) + 8 * i;
        float4 v = *(const float4*)(Csf + row * 132 + col);
        *(float4*)(C + (size_t)(bm * 128 + p * 64 + row) * ldc + bn * 128 + col) = v;
      }
      if (p == 0) __syncthreads();
    }
  }
}

// ---------------------------------------------------------------------------
// kernel_launch
// inputs: d_in[0]=x (4096x2048 f32), d_in[1]=weights (7168x7168 f32),
//         d_in[2]=structure_mask (unused — mask is 1 over every slice we read)
// out: 4096x1024 f32
// ws: A2 bf16 4096x6144 | Bt1 bf16 4096x2048 | Bt2 bf16 1024x6144 |
//     P fp32 4 x (4096x1024)   (total ~147 MB)
// ---------------------------------------------------------------------------
extern "C" void kernel_launch(void* const* d_in, const int* in_sizes, int n_in,
                              void* d_out, int out_size, void* d_ws, size_t ws_size,
                              hipStream_t stream) {
  const float* x = (const float*)d_in[0];
  const float* W = (const float*)d_in[1];

  char* ws = (char*)d_ws;
  const size_t A2_BYTES  = (size_t)BATCH * LDA2 * 2;       // 50,331,648
  const size_t BT1_BYTES = (size_t)N_HID * N_IN * 2;       // 16,777,216
  const size_t BT2_BYTES = (size_t)N_OUT * LDA2 * 2;       // 12,582,912
  unsigned short* A2  = (unsigned short*)ws;
  unsigned short* Bt1 = (unsigned short*)(ws + A2_BYTES);
  unsigned short* Bt2 = (unsigned short*)(ws + A2_BYTES + BT1_BYTES);
  float*          P   = (float*)(ws + A2_BYTES + BT1_BYTES + BT2_BYTES);

  // 1) x -> bf16 into A2[:, 0:2048]
  conv_x_kernel<<<(BATCH * N_IN / 4) / 256, 256, 0, stream>>>(x, A2);

  // 2) Bt1[n][k] = W[k][2048+n], k<2048, n<4096  (W1^T)
  conv_t_kernel<<<dim3(N_HID / 32, N_IN / 32), 256, 0, stream>>>(
      W + N_IN, N_TOT, Bt1, N_IN, N_IN, N_HID);

  // 3) Bt2[n][k] = W[k][6144+n], k<6144, n<1024  ([W2;W3]^T)
  conv_t_kernel<<<dim3(N_OUT / 32, LDA2 / 32), 256, 0, stream>>>(
      W + N_IN + N_HID, N_TOT, Bt2, LDA2, LDA2, N_OUT);

  // 4) H = relu(x @ W1) -> bf16 into A2[:, 2048:6144]
  gemm_bt<1><<<dim3(N_HID / 128, BATCH / 128), 256, 0, stream>>>(
      A2, LDA2, Bt1, N_IN, A2 + N_IN, LDA2, N_IN, 0);

  // 5) partials: P[z] = A2[:, z*1536:(z+1)*1536] @ Bt2^T slice  (split-K=4,
  //    single-writer per buffer -> deterministic, no atomics)
  gemm_bt<0><<<dim3(N_OUT / 128, BATCH / 128, 4), 256, 0, stream>>>(
      A2, LDA2, Bt2, LDA2, P, N_OUT, LDA2 / 4, OUT_ELEMS);

  // 6) out = P0 + P1 + P2 + P3
  add4_kernel<<<(OUT_ELEMS / 4) / 256, 256, 0, stream>>>(P, (float*)d_out);
}

// Round 4
// 507.454 us; speedup vs baseline: 1.0321x; 1.0321x over previous
//
#include <hip/hip_runtime.h>
#include <hip/hip_bf16.h>

// Problem constants
#define N_IN  2048
#define N_HID 4096
#define N_OUT 1024
#define N_TOT 7168
#define BATCH 4096
#define LDA2  (N_IN + N_HID)   // 6144: [x | H] activation buffer leading dim
#define OUT_ELEMS ((size_t)BATCH * N_OUT)

typedef __attribute__((ext_vector_type(8))) short short8;
typedef __attribute__((ext_vector_type(4))) float f32x4;

static __device__ __forceinline__ unsigned short f2bf(float f) {
  __hip_bfloat16 h = __float2bfloat16(f);
  return __builtin_bit_cast(unsigned short, h);
}

// ---------------------------------------------------------------------------
// Convert x (BATCH x N_IN fp32) -> bf16 into A2[:, 0:2048] (row stride 6144)
// ---------------------------------------------------------------------------
__global__ void conv_x_kernel(const float* __restrict__ x,
                              unsigned short* __restrict__ A2) {
  int idx = blockIdx.x * 256 + threadIdx.x;     // BATCH*N_IN/4 threads
  int row = idx >> 9;                           // N_IN/4 = 512 groups per row
  int col = (idx & 511) << 2;
  const float4 v = *(const float4*)(x + (size_t)row * N_IN + col);
  ushort4 o;
  o.x = f2bf(v.x); o.y = f2bf(v.y); o.z = f2bf(v.z); o.w = f2bf(v.w);
  *(ushort4*)(A2 + (size_t)row * LDA2 + col) = o;
}

// ---------------------------------------------------------------------------
// Transpose-convert: dst[n][k] = (bf16)src[k][n]
// src: SK x SN fp32 region with row stride lds_; dst: SN x SK bf16, stride ldd
// 32x32 tiles, 256 threads.
// ---------------------------------------------------------------------------
__global__ void conv_t_kernel(const float* __restrict__ src, int lds_,
                              unsigned short* __restrict__ dst, int ldd) {
  __shared__ float tile[32][33];
  const int t = threadIdx.x;
  const int k0 = blockIdx.y << 5, n0 = blockIdx.x << 5;
  const int r = t >> 3, c = (t & 7) << 2;
  const float4 v = *(const float4*)(src + (size_t)(k0 + r) * lds_ + n0 + c);
  tile[r][c] = v.x; tile[r][c + 1] = v.y; tile[r][c + 2] = v.z; tile[r][c + 3] = v.w;
  __syncthreads();
  ushort4 o;
  o.x = f2bf(tile[c][r]);
  o.y = f2bf(tile[c + 1][r]);
  o.z = f2bf(tile[c + 2][r]);
  o.w = f2bf(tile[c + 3][r]);
  *(ushort4*)(dst + (size_t)(n0 + r) * ldd + k0 + c) = o;
}

// ---------------------------------------------------------------------------
// out = P0 + P1 + P2 (float4, coalesced). Fixed order -> deterministic.
// ---------------------------------------------------------------------------
__global__ void add3_kernel(const float* __restrict__ P, float* __restrict__ out) {
  size_t i = ((size_t)blockIdx.x * 256 + threadIdx.x) * 4;
  float4 a = *(const float4*)(P + i);
  float4 b = *(const float4*)(P + OUT_ELEMS + i);
  float4 c = *(const float4*)(P + 2 * OUT_ELEMS + i);
  float4 o;
  o.x = (a.x + b.x) + c.x;
  o.y = (a.y + b.y) + c.y;
  o.z = (a.z + b.z) + c.z;
  o.w = (a.w + b.w) + c.w;
  *(float4*)(out + i) = o;
}

// ===========================================================================
// Shared GEMM machinery: 128x128 tile, BK=64, 4 waves x (64x64),
// 16x16x32 bf16 MFMA, global_load_lds width-16 staging, XOR-swizzled LDS
// (staging permutes per-lane global source column; readers XOR chunk index
// with row&7 -> ds_read_b128 is 2-way max, free per m136).
// ===========================================================================
struct GemmCtx {
  int lane, wave, wy, wx, lm, quad;
  int grow, gcol;
};

static __device__ __forceinline__ void gemm_kloop(
    const unsigned short* __restrict__ Ag, int lda,
    const unsigned short* __restrict__ Bg, int ldb,
    unsigned short* As, unsigned short* Bs, const GemmCtx& cx,
    int Klen, f32x4 acc[4][4]) {
  unsigned short* Asl = As + cx.wave * 2048;
  unsigned short* Bsl = Bs + cx.wave * 2048;
  for (int ko = 0; ko < Klen; ko += 64) {
    __syncthreads();   // previous iter's compute done before overwrite
#pragma unroll
    for (int i = 0; i < 4; ++i) {
      __builtin_amdgcn_global_load_lds(
          (const __attribute__((address_space(1))) void*)(Ag + (size_t)(8 * i) * lda + ko),
          (__attribute__((address_space(3))) void*)(Asl + i * 512), 16, 0, 0);
      __builtin_amdgcn_global_load_lds(
          (const __attribute__((address_space(1))) void*)(Bg + (size_t)(8 * i) * ldb + ko),
          (__attribute__((address_space(3))) void*)(Bsl + i * 512), 16, 0, 0);
    }
    __syncthreads();   // s_waitcnt vmcnt(0) + barrier

#pragma unroll
    for (int kk = 0; kk < 2; ++kk) {
      short8 av[4], bv[4];
#pragma unroll
      for (int mt = 0; mt < 4; ++mt) {
        const int r = cx.wy * 64 + mt * 16 + cx.lm;
        av[mt] = *(const short8*)(As + r * 64 + (((kk * 4 + cx.quad) ^ (cx.lm & 7)) << 3));
      }
#pragma unroll
      for (int nt = 0; nt < 4; ++nt) {
        const int r = cx.wx * 64 + nt * 16 + cx.lm;
        bv[nt] = *(const short8*)(Bs + r * 64 + (((kk * 4 + cx.quad) ^ (cx.lm & 7)) << 3));
      }
#pragma unroll
      for (int mt = 0; mt < 4; ++mt)
#pragma unroll
        for (int nt = 0; nt < 4; ++nt)
          acc[mt][nt] = __builtin_amdgcn_mfma_f32_16x16x32_bf16(
              av[mt], bv[nt], acc[mt][nt], 0, 0, 0);
    }
  }
}

// fp32 epilogue: two 64x128 passes through LDS (stride 132 floats,
// conflict-free write phase), coalesced float4 stores.
static __device__ __forceinline__ void epilogue_f32(
    char* smem, const GemmCtx& cx, f32x4 acc[4][4],
    float* __restrict__ C, int ldc, int row_base, int col_base, int tid) {
  float* Csf = (float*)smem;
#pragma unroll
  for (int p = 0; p < 2; ++p) {
    if (cx.wy == p) {
#pragma unroll
      for (int mt = 0; mt < 4; ++mt) {
        const int row0 = mt * 16 + cx.quad * 4;
#pragma unroll
        for (int nt = 0; nt < 4; ++nt) {
          const int col = cx.wx * 64 + nt * 16 + cx.lm;
#pragma unroll
          for (int r = 0; r < 4; ++r)
            Csf[(row0 + r) * 132 + col] = acc[mt][nt][r];
        }
      }
    }
    __syncthreads();
    const int col = (tid & 31) << 2;      // 32 lanes x 16B = 512B per row
#pragma unroll
    for (int i = 0; i < 8; ++i) {
      const int row = (tid >> 5) + 8 * i;
      float4 v = *(const float4*)(Csf + row * 132 + col);
      *(float4*)(C + (size_t)(row_base + p * 64 + row) * ldc + col_base + col) = v;
    }
    if (p == 0) __syncthreads();
  }
}

// ---------------------------------------------------------------------------
// Fused GEMM1: [H | P0] = relu_split(x2 @ [W1 | W2])
// grid (40, 32): bn<32 -> relu+bf16 into A2[:,2048+bn*128..] (ldc 6144);
// bn>=32 -> fp32 into P0 (ldc 1024). K=2048. 1280 blocks = 4-5/CU.
// ---------------------------------------------------------------------------
__global__ __launch_bounds__(256)
void gemm_fused(const unsigned short* __restrict__ A, int lda,
                const unsigned short* __restrict__ Bt, int ldb,
                unsigned short* __restrict__ Hout,
                float* __restrict__ P0) {
  __shared__ __align__(16) char smem[34816];
  unsigned short* As = (unsigned short*)smem;
  unsigned short* Bs = (unsigned short*)(smem + 16384);

  const int tid = threadIdx.x;
  GemmCtx cx;
  cx.lane = tid & 63; cx.wave = tid >> 6;
  cx.wy = cx.wave >> 1; cx.wx = cx.wave & 1;
  cx.lm = cx.lane & 15; cx.quad = cx.lane >> 4;
  cx.grow = (cx.wave << 5) + (cx.lane >> 3);
  cx.gcol = ((cx.lane & 7) ^ (cx.lane >> 3)) << 3;
  const int bm = blockIdx.y, bn = blockIdx.x;

  const unsigned short* Ag = A  + (size_t)(bm * 128 + cx.grow) * lda + cx.gcol;
  const unsigned short* Bg = Bt + (size_t)(bn * 128 + cx.grow) * ldb + cx.gcol;

  f32x4 acc[4][4];
#pragma unroll
  for (int i = 0; i < 4; ++i)
#pragma unroll
    for (int j = 0; j < 4; ++j)
      acc[i][j] = (f32x4){0.f, 0.f, 0.f, 0.f};

  gemm_kloop(Ag, lda, Bg, ldb, As, Bs, cx, N_IN, acc);

  __syncthreads();   // all waves done reading As/Bs before smem reuse

  if (bn < 32) {
    // relu + bf16, full 128x128 tile in LDS, padded stride 136 shorts.
    unsigned short* Cs = (unsigned short*)smem;
#pragma unroll
    for (int mt = 0; mt < 4; ++mt) {
      const int row0 = cx.wy * 64 + mt * 16 + cx.quad * 4;
#pragma unroll
      for (int nt = 0; nt < 4; ++nt) {
        const int col = cx.wx * 64 + nt * 16 + cx.lm;
#pragma unroll
        for (int r = 0; r < 4; ++r) {
          float v = acc[mt][nt][r];
          Cs[(row0 + r) * 136 + col] = f2bf(v > 0.f ? v : 0.f);
        }
      }
    }
    __syncthreads();
    const int col = (tid & 15) << 3;        // 16 lanes x 16B = 256B per row
#pragma unroll
    for (int i = 0; i < 8; ++i) {
      const int row = (tid >> 4) + 16 * i;
      short8 v = *(const short8*)(Cs + row * 136 + col);
      *(short8*)(Hout + (size_t)(bm * 128 + row) * LDA2 + bn * 128 + col) = v;
    }
  } else {
    epilogue_f32(smem, cx, acc, P0, N_OUT, bm * 128, (bn - 32) * 128, tid);
  }
}

// ---------------------------------------------------------------------------
// GEMM2: P[1+z] = H[:, z*2048:(z+1)*2048] @ W3-slice. grid (8, 32, 2).
// Single-writer per partial -> deterministic, no atomics.
// ---------------------------------------------------------------------------
__global__ __launch_bounds__(256)
void gemm_p(const unsigned short* __restrict__ A, int lda,
            const unsigned short* __restrict__ Bt, int ldb,
            float* __restrict__ P) {
  __shared__ __align__(16) char smem[34816];
  unsigned short* As = (unsigned short*)smem;
  unsigned short* Bs = (unsigned short*)(smem + 16384);

  const int tid = threadIdx.x;
  GemmCtx cx;
  cx.lane = tid & 63; cx.wave = tid >> 6;
  cx.wy = cx.wave >> 1; cx.wx = cx.wave & 1;
  cx.lm = cx.lane & 15; cx.quad = cx.lane >> 4;
  cx.grow = (cx.wave << 5) + (cx.lane >> 3);
  cx.gcol = ((cx.lane & 7) ^ (cx.lane >> 3)) << 3;
  const int bm = blockIdx.y, bn = blockIdx.x;
  const int ko0 = blockIdx.z * 2048;

  const unsigned short* Ag = A  + (size_t)(bm * 128 + cx.grow) * lda + cx.gcol + ko0;
  const unsigned short* Bg = Bt + (size_t)(bn * 128 + cx.grow) * ldb + cx.gcol + ko0;

  f32x4 acc[4][4];
#pragma unroll
  for (int i = 0; i < 4; ++i)
#pragma unroll
    for (int j = 0; j < 4; ++j)
      acc[i][j] = (f32x4){0.f, 0.f, 0.f, 0.f};

  gemm_kloop(Ag, lda, Bg, ldb, As, Bs, cx, 2048, acc);

  __syncthreads();
  epilogue_f32(smem, cx, acc, P + (size_t)blockIdx.z * OUT_ELEMS, N_OUT,
               bm * 128, bn * 128, tid);
}

// ---------------------------------------------------------------------------
// kernel_launch
// inputs: d_in[0]=x (4096x2048 f32), d_in[1]=weights (7168x7168 f32),
//         d_in[2]=structure_mask (unused — mask is 1 over every slice we read)
// out: 4096x1024 f32
// ws: A2 bf16 4096x6144 (50.3MB) | Bt12 bf16 5120x2048 (21.0MB) |
//     Bt3 bf16 1024x4096 (8.4MB) | P fp32 3 x (4096x1024) (50.3MB)
// ---------------------------------------------------------------------------
extern "C" void kernel_launch(void* const* d_in, const int* in_sizes, int n_in,
                              void* d_out, int out_size, void* d_ws, size_t ws_size,
                              hipStream_t stream) {
  const float* x = (const float*)d_in[0];
  const float* W = (const float*)d_in[1];

  char* ws = (char*)d_ws;
  const size_t A2_BYTES   = (size_t)BATCH * LDA2 * 2;
  const size_t BT12_BYTES = (size_t)(N_HID + N_OUT) * N_IN * 2;
  const size_t BT3_BYTES  = (size_t)N_OUT * N_HID * 2;
  unsigned short* A2   = (unsigned short*)ws;
  unsigned short* Bt12 = (unsigned short*)(ws + A2_BYTES);
  unsigned short* Bt3  = (unsigned short*)(ws + A2_BYTES + BT12_BYTES);
  float*          P    = (float*)(ws + A2_BYTES + BT12_BYTES + BT3_BYTES);

  // 1) x -> bf16 into A2[:, 0:2048]
  conv_x_kernel<<<(BATCH * N_IN / 4) / 256, 256, 0, stream>>>(x, A2);

  // 2) Bt12[n][k] = W[k][2048+n], k<2048, n<5120  ([W1 | W2]^T, contiguous cols)
  conv_t_kernel<<<dim3((N_HID + N_OUT) / 32, N_IN / 32), 256, 0, stream>>>(
      W + N_IN, N_TOT, Bt12, N_IN);

  // 3) Bt3[n][k] = W[2048+k][6144+n], k<4096, n<1024  (W3^T)
  conv_t_kernel<<<dim3(N_OUT / 32, N_HID / 32), 256, 0, stream>>>(
      W + (size_t)N_IN * N_TOT + N_IN + N_HID, N_TOT, Bt3, N_HID);

  // 4) fused: H = relu(x@W1) -> A2[:,2048:], and P0 = x@W2 (fp32)
  gemm_fused<<<dim3((N_HID + N_OUT) / 128, BATCH / 128), 256, 0, stream>>>(
      A2, LDA2, Bt12, N_IN, A2 + N_IN, P);

  // 5) P1,P2 = H @ W3 split-K=2 (single-writer partials)
  gemm_p<<<dim3(N_OUT / 128, BATCH / 128, 2), 256, 0, stream>>>(
      A2 + N_IN, LDA2, Bt3, N_HID, P + OUT_ELEMS);

  // 6) out = P0 + P1 + P2
  add3_kernel<<<(OUT_ELEMS / 4) / 256, 256, 0, stream>>>(P, (float*)d_out);
}